// Round 11
// baseline (651.989 us; speedup 1.0000x reference)
//
#include <hip/hip_runtime.h>
#include <math.h>
#include <stdint.h>

#define BATCH 16
#define RDIM 2048
#define UDIM 2048
#define DDIM 1024

typedef __attribute__((ext_vector_type(8))) short short8;
typedef __attribute__((ext_vector_type(4))) float f32x4;
typedef __attribute__((ext_vector_type(8))) unsigned short ushort8;
typedef __attribute__((ext_vector_type(4))) unsigned short ushort4v;
typedef __attribute__((ext_vector_type(4))) float float4v;

__device__ __forceinline__ float bf2f(unsigned short u) {
  unsigned int x = ((unsigned int)u) << 16;
  return __builtin_bit_cast(float, x);
}
__device__ __forceinline__ unsigned short f2bf(float f) {
  unsigned int x = __builtin_bit_cast(unsigned int, f);
  unsigned int r = (x + 0x7fffu + ((x >> 16) & 1u)) >> 16;
  return (unsigned short)r;
}

__device__ __forceinline__ void gload_lds16(const void* g, void* l) {
  __builtin_amdgcn_global_load_lds(
      (const __attribute__((address_space(1))) void*)(uintptr_t)g,
      (__attribute__((address_space(3))) void*)(uint32_t)(uintptr_t)l,
      16, 0, 0);
}

#define FENCE() __builtin_amdgcn_sched_barrier(0)
#define BAR() __builtin_amdgcn_s_barrier()
#define LGKM0() asm volatile("s_waitcnt lgkmcnt(0)" ::: "memory")
#define LGKM8() asm volatile("s_waitcnt lgkmcnt(8)" ::: "memory")
#define VMCNT6() asm volatile("s_waitcnt vmcnt(6)" ::: "memory")
#define VMCNT0() asm volatile("s_waitcnt vmcnt(0)" ::: "memory")

// ---------------- conversions ----------------

// y=0: Q -> Qb (scaled); y=1: K -> Kb
__global__ __launch_bounds__(256) void k_conv2(const float* __restrict__ Q,
                                               const float* __restrict__ Kin,
                                               unsigned short* __restrict__ Qb,
                                               unsigned short* __restrict__ Kb,
                                               float scale) {
  const float* in = blockIdx.y ? Kin : Q;
  unsigned short* out = blockIdx.y ? Kb : Qb;
  const float s = blockIdx.y ? 1.0f : scale;
  const long i = ((long)blockIdx.x * 256 + threadIdx.x) * 8;
  float4v a = *(const float4v*)(in + i);
  float4v b = *(const float4v*)(in + i + 4);
  ushort8 o;
#pragma unroll
  for (int j = 0; j < 4; ++j) o[j] = f2bf(a[j] * s);
#pragma unroll
  for (int j = 0; j < 4; ++j) o[4 + j] = f2bf(b[j] * s);
  *(ushort8*)(out + i) = o;
}

// out[c*rows + r] = bf16(in[r*cols + c])
__global__ void k_transpose_bf16(const float* __restrict__ in,
                                 unsigned short* __restrict__ out,
                                 int rows, int cols, long sIn, long sOut) {
  __shared__ unsigned short tile[64][65];
  const long bz = blockIdx.z;
  in += bz * sIn;
  out += bz * sOut;
  const int r0 = blockIdx.x * 64;
  const int c0 = blockIdx.y * 64;
  const int tx = threadIdx.x;  // 64
  const int ty = threadIdx.y;  // 4
#pragma unroll
  for (int i = 0; i < 16; ++i) {
    const int r = ty + i * 4;
    tile[r][tx] = f2bf(in[(long)(r0 + r) * cols + c0 + tx]);
  }
  __syncthreads();
#pragma unroll
  for (int i = 0; i < 16; ++i) {
    const int r = ty + i * 4;
    out[(long)(c0 + r) * rows + r0 + tx] = tile[tx][r];
  }
}

// ---------------- GEMM: C[M,N] = A[M,K] * B[N,K]^T, bf16 in, fp32 acc -------
// Core = r9 (m201 8-phase, counted vmcnt(6), PMC-verified 0 bank conflicts).
// EPI 1: store bf16 relu(acc + bias[col]) (FFN1)
// EPI 3: store bf16 exp(acc) + per-block row-sum partials (softmax numerator;
//        max-shift dropped: |S|<~6 so exp is safe)     -> part[grow*8+by]
// EPI 4: y = acc + bias + bf2f(res); store bf16 y + LN partials
//        -> part[grow*8 + by*2 + {0:sum,1:sumsq}]
// EPI 5 (PV+addln fused): v = resf[row,col] + acc*rs(row) with rs from `part`
//        (S row-sums, cached in LDS per block, broadcast reads); store bf16
//        Xraw; LN partials -> part2[grow*8 + by*2 + {0,1}]

template <int EPI>
__global__ __launch_bounds__(512, 1) void gemm_bt(
    const unsigned short* __restrict__ A, const unsigned short* __restrict__ B,
    void* __restrict__ Cout, int N, int K, long sA, long sB, long sC,
    const float* __restrict__ bias, const unsigned short* __restrict__ res,
    float* __restrict__ part, const float* __restrict__ resf,
    float* __restrict__ part2) {
  __shared__ __align__(128) unsigned short lds[2][2][2][256 * 32];  // 128 KiB

  // ---- T1: XCD-aware bijective remap (all grids are multiples of 8) ----
  int lin = blockIdx.x + gridDim.x * (blockIdx.y + gridDim.y * blockIdx.z);
  lin = (lin & 7) * ((gridDim.x * gridDim.y * gridDim.z) >> 3) + (lin >> 3);
  const int by = lin % gridDim.y;  // y-fastest: share A-panel in L2
  int rest = lin / gridDim.y;
  const int bx = rest % gridDim.x;
  const int bz = rest / gridDim.x;

  const unsigned short* Ab = A + (long)bz * sA;
  const unsigned short* Bb = B + (long)bz * sB;

  const int tid = threadIdx.x;
  const int w = tid >> 6;  // 0..7
  const int lane = tid & 63;
  const int wm = w >> 2;   // 0..1
  const int wn = w & 3;    // 0..3
  const long rowBase = (long)bx * 256;
  const long colBase = (long)by * 256;

  // ---- staging addressing (involution verified 0-conflict, r4-r10) ----
  const int s = tid >> 2;                          // 0..127
  const int kslot = (tid & 3) ^ ((tid >> 3) & 3);  // logical 16B slot
  const int lRowA = s + (s & 64);                  // + h*64 at use
  const int lRowB = ((s & 96) << 1) + (s & 31);    // + h*32 at use
  const unsigned short* gA0 = Ab + (long)(rowBase + lRowA) * K + kslot * 8;
  const unsigned short* gB0 = Bb + (long)(colBase + lRowB) * K + kslot * 8;
  char* ldsB = (char*)&lds[0][0][0][0];
  const int wOff = w * 1024;

  auto STAGE_A = [&](int buf, int h, int kt) {
    const unsigned short* g = gA0 + (long)(h * 64) * K + kt * 64;
    char* d = ldsB + ((buf * 4 + 0) << 14) + h * 8192 + wOff;
    gload_lds16(g, d);
    gload_lds16(g + 32, d + 16384);
  };
  auto STAGE_B = [&](int buf, int h, int kt) {
    const unsigned short* g = gB0 + (long)(h * 32) * K + kt * 64;
    char* d = ldsB + ((buf * 4 + 2) << 14) + h * 8192 + wOff;
    gload_lds16(g, d);
    gload_lds16(g + 32, d + 16384);
  };

  const int laneM = lane & 15;
  const int laneQ = lane >> 4;
  const int swz = (laneQ ^ ((laneM >> 1) & 3)) << 4;
  const int rdA = (wm * 64 + laneM) * 64 + swz;
  const int rdB = (wn * 32 + laneM) * 64 + swz;

  f32x4 acc[8][4] = {};
  const int NT = K >> 6;
  const int NI = NT >> 1;

  short8 A0[4][2], A1[4][2], B0[2][2], B1[2][2];

  auto RD_A = [&](short8 (&dst)[4][2], int buf, int h) {
#pragma unroll
    for (int mm = 0; mm < 4; ++mm)
#pragma unroll
      for (int kk = 0; kk < 2; ++kk)
        dst[mm][kk] = *(const short8*)(ldsB + ((buf * 4 + kk) << 14) +
                                       h * 8192 + rdA + mm * 1024);
  };
  auto RD_B = [&](short8 (&dst)[2][2], int buf, int h) {
#pragma unroll
    for (int nn = 0; nn < 2; ++nn)
#pragma unroll
      for (int kk = 0; kk < 2; ++kk)
        dst[nn][kk] = *(const short8*)(ldsB + ((buf * 4 + 2 + kk) << 14) +
                                       h * 8192 + rdB + nn * 1024);
  };

#define MFMAQ(AF, BF, MB, NB)                                                  \
  __builtin_amdgcn_s_setprio(1);                                               \
  _Pragma("unroll") for (int mm = 0; mm < 4; ++mm)                             \
  _Pragma("unroll") for (int nn = 0; nn < 2; ++nn)                             \
  _Pragma("unroll") for (int kk = 0; kk < 2; ++kk)                             \
      acc[MB + mm][NB + nn] = __builtin_amdgcn_mfma_f32_16x16x32_bf16(         \
          AF[mm][kk], BF[nn][kk], acc[MB + mm][NB + nn], 0, 0, 0);             \
  __builtin_amdgcn_s_setprio(0);

  STAGE_A(0, 0, 0); STAGE_B(0, 0, 0); STAGE_B(0, 1, 0); STAGE_A(0, 1, 0);
  STAGE_A(1, 0, 1); STAGE_B(1, 0, 1); STAGE_B(1, 1, 1);
  VMCNT6();
  BAR();
  FENCE();

  for (int i = 0; i < NI; ++i) {
    const int t1 = 2 * i + 1;
    const int t2 = (2 * i + 2 <= NT - 1) ? 2 * i + 2 : NT - 1;
    const int t3 = (2 * i + 3 <= NT - 1) ? 2 * i + 3 : NT - 1;

    // ===== K-tile buf0 =====
    RD_A(A0, 0, 0); RD_B(B0, 0, 0);
    STAGE_A(1, 1, t1);
    LGKM8(); BAR(); LGKM0(); FENCE();
    MFMAQ(A0, B0, 0, 0);
    BAR();

    RD_B(B1, 0, 1);
    STAGE_A(0, 0, t2);
    BAR(); LGKM0(); FENCE();
    MFMAQ(A0, B1, 0, 2);
    BAR();

    RD_A(A1, 0, 1);
    STAGE_B(0, 0, t2);
    BAR(); LGKM0(); FENCE();
    MFMAQ(A1, B1, 4, 2);
    BAR();

    STAGE_B(0, 1, t2);
    VMCNT6(); BAR(); FENCE();
    MFMAQ(A1, B0, 4, 0);
    BAR();

    // ===== K-tile buf1 =====
    RD_A(A0, 1, 0); RD_B(B0, 1, 0);
    STAGE_A(0, 1, t2);
    LGKM8(); BAR(); LGKM0(); FENCE();
    MFMAQ(A0, B0, 0, 0);
    BAR();

    RD_B(B1, 1, 1);
    STAGE_A(1, 0, t3);
    BAR(); LGKM0(); FENCE();
    MFMAQ(A0, B1, 0, 2);
    BAR();

    RD_A(A1, 1, 1);
    STAGE_B(1, 0, t3);
    BAR(); LGKM0(); FENCE();
    MFMAQ(A1, B1, 4, 2);
    BAR();

    STAGE_B(1, 1, t3);
    VMCNT6(); BAR(); FENCE();
    MFMAQ(A1, B0, 4, 0);
    BAR();
  }
  VMCNT0();  // all trailing stage-writes to LDS landed (per-wave)
  BAR();     // ...block-wide, so LDS is safe to reuse as scratch below
#undef MFMAQ

  const long r0 = rowBase + wm * 128;
  const long c0 = colBase + wn * 64;
  const int cr = laneQ << 2;
  const int cc = laneM;

  if constexpr (EPI == 1) {
    unsigned short* C = (unsigned short*)Cout;
#pragma unroll
    for (int i = 0; i < 8; ++i)
#pragma unroll
      for (int j = 0; j < 4; ++j)
#pragma unroll
        for (int jj = 0; jj < 4; ++jj) {
          const long col = c0 + j * 16 + cc;
          float v = acc[i][j][jj] + bias[col];
          v = fmaxf(v, 0.f);
          C[(r0 + i * 16 + cr + jj) * N + col] = f2bf(v);
        }
  } else if constexpr (EPI == 3) {
    // exp + row-sum partials (softmax numerator; PV normalizes later)
    unsigned short* C = (unsigned short*)Cout + (long)bz * sC;
    float rp[8][4];
#pragma unroll
    for (int i = 0; i < 8; ++i)
#pragma unroll
      for (int jj = 0; jj < 4; ++jj) rp[i][jj] = 0.f;
#pragma unroll
    for (int i = 0; i < 8; ++i)
#pragma unroll
      for (int j = 0; j < 4; ++j)
#pragma unroll
        for (int jj = 0; jj < 4; ++jj) {
          float e = __expf(acc[i][j][jj]);
          C[(r0 + i * 16 + cr + jj) * N + (c0 + j * 16 + cc)] = f2bf(e);
          rp[i][jj] += e;
        }
    float* sm = (float*)ldsB;
#pragma unroll
    for (int i = 0; i < 8; ++i)
#pragma unroll
      for (int jj = 0; jj < 4; ++jj) {
        float r4 = rp[i][jj];
        r4 += __shfl_xor(r4, 8);
        r4 += __shfl_xor(r4, 4);
        r4 += __shfl_xor(r4, 2);
        r4 += __shfl_xor(r4, 1);
        if (cc == 0) sm[wn * 256 + wm * 128 + i * 16 + cr + jj] = r4;
      }
    BAR();
    if (tid < 256) {
      float ssum = sm[tid] + sm[256 + tid] + sm[512 + tid] + sm[768 + tid];
      part[((long)bz * RDIM + rowBase + tid) * 8 + by] = ssum;
    }
  } else if constexpr (EPI == 4) {
    // y bf16 + LN partials
    unsigned short* C = (unsigned short*)Cout;
    float rp1[8][4], rp2[8][4];
#pragma unroll
    for (int i = 0; i < 8; ++i)
#pragma unroll
      for (int jj = 0; jj < 4; ++jj) { rp1[i][jj] = 0.f; rp2[i][jj] = 0.f; }
#pragma unroll
    for (int i = 0; i < 8; ++i)
#pragma unroll
      for (int j = 0; j < 4; ++j)
#pragma unroll
        for (int jj = 0; jj < 4; ++jj) {
          const long row = r0 + i * 16 + cr + jj;
          const long col = c0 + j * 16 + cc;
          float v = acc[i][j][jj] + bias[col] + bf2f(res[row * N + col]);
          C[row * N + col] = f2bf(v);
          rp1[i][jj] += v;
          rp2[i][jj] += v * v;
        }
    float* sm = (float*)ldsB;
#pragma unroll
    for (int i = 0; i < 8; ++i)
#pragma unroll
      for (int jj = 0; jj < 4; ++jj) {
        float r4 = rp1[i][jj], q4 = rp2[i][jj];
        r4 += __shfl_xor(r4, 8); q4 += __shfl_xor(q4, 8);
        r4 += __shfl_xor(r4, 4); q4 += __shfl_xor(q4, 4);
        r4 += __shfl_xor(r4, 2); q4 += __shfl_xor(q4, 2);
        r4 += __shfl_xor(r4, 1); q4 += __shfl_xor(q4, 1);
        if (cc == 0) {
          sm[wn * 256 + wm * 128 + i * 16 + cr + jj] = r4;
          sm[1024 + wn * 256 + wm * 128 + i * 16 + cr + jj] = q4;
        }
      }
    BAR();
    if (tid < 256) {
      float s1 = sm[tid] + sm[256 + tid] + sm[512 + tid] + sm[768 + tid];
      float s2 = sm[1024 + tid] + sm[1280 + tid] + sm[1536 + tid] + sm[1792 + tid];
      part[(rowBase + tid) * 8 + by * 2] = s1;
      part[(rowBase + tid) * 8 + by * 2 + 1] = s2;
    }
  } else {
    // EPI 5: Xraw = resf + acc*rs(row); bf16 store + LN partials -> part2
    unsigned short* C = (unsigned short*)Cout + (long)bz * sC;
    const float* Qf = resf + (long)bz * sC;
    float* rsl = (float*)ldsB;               // [256] per-row 1/rowsum
    float* sm = (float*)(ldsB + 8192);       // reduction scratch (disjoint)
    if (tid < 256) {
      const float* p = part + ((long)bz * RDIM + rowBase + tid) * 8;
      rsl[tid] = 1.0f /
          (((p[0] + p[1]) + (p[2] + p[3])) + ((p[4] + p[5]) + (p[6] + p[7])));
    }
    BAR();
    float rp1[8][4], rp2[8][4];
#pragma unroll
    for (int i = 0; i < 8; ++i)
#pragma unroll
      for (int jj = 0; jj < 4; ++jj) { rp1[i][jj] = 0.f; rp2[i][jj] = 0.f; }
#pragma unroll
    for (int i = 0; i < 8; ++i)
#pragma unroll
      for (int j = 0; j < 4; ++j)
#pragma unroll
        for (int jj = 0; jj < 4; ++jj) {
          const int lr = wm * 128 + i * 16 + cr + jj;
          const long row = rowBase + lr;
          const long col = c0 + j * 16 + cc;
          float v = Qf[row * N + col] + acc[i][j][jj] * rsl[lr];
          C[row * N + col] = f2bf(v);
          rp1[i][jj] += v;
          rp2[i][jj] += v * v;
        }
#pragma unroll
    for (int i = 0; i < 8; ++i)
#pragma unroll
      for (int jj = 0; jj < 4; ++jj) {
        float r4 = rp1[i][jj], q4 = rp2[i][jj];
        r4 += __shfl_xor(r4, 8); q4 += __shfl_xor(q4, 8);
        r4 += __shfl_xor(r4, 4); q4 += __shfl_xor(q4, 4);
        r4 += __shfl_xor(r4, 2); q4 += __shfl_xor(q4, 2);
        r4 += __shfl_xor(r4, 1); q4 += __shfl_xor(q4, 1);
        if (cc == 0) {
          sm[wn * 256 + wm * 128 + i * 16 + cr + jj] = r4;
          sm[1024 + wn * 256 + wm * 128 + i * 16 + cr + jj] = q4;
        }
      }
    BAR();
    if (tid < 256) {
      float s1 = sm[tid] + sm[256 + tid] + sm[512 + tid] + sm[768 + tid];
      float s2 = sm[1024 + tid] + sm[1280 + tid] + sm[1536 + tid] + sm[1792 + tid];
      part2[((long)bz * RDIM + rowBase + tid) * 8 + by * 2] = s1;
      part2[((long)bz * RDIM + rowBase + tid) * 8 + by * 2 + 1] = s2;
    }
  }
}

// ---- X normalize in-place (bf16), stats from PV partials ----

__global__ __launch_bounds__(256) void k_ln_x(
    unsigned short* __restrict__ X, const float* __restrict__ lnP,
    const float* __restrict__ gamma, const float* __restrict__ beta) {
  const long row = blockIdx.x;
  const long base = row * DDIM;
  const int t = threadIdx.x;
  const float* p = lnP + row * 8;
  const float s1 = (p[0] + p[2]) + (p[4] + p[6]);
  const float s2 = (p[1] + p[3]) + (p[5] + p[7]);
  const float mu = s1 * (1.f / DDIM);
  const float var = s2 * (1.f / DDIM) - mu * mu;
  const float rstd = rsqrtf(var + 1e-6f);
  ushort4v v = *(const ushort4v*)(X + base + t * 4);
  ushort4v o;
#pragma unroll
  for (int j = 0; j < 4; ++j) {
    const int c = t * 4 + j;
    o[j] = f2bf(gamma[c] * ((bf2f(v[j]) - mu) * rstd) + beta[c]);
  }
  *(ushort4v*)(X + base + t * 4) = o;
}

// ---- final LN: out = gamma*(y-mu)*rstd+beta, stats from FFN2 partials ----

__global__ __launch_bounds__(256) void k_ln_final(
    const unsigned short* __restrict__ y, const float* __restrict__ lnP,
    float* __restrict__ out, const float* __restrict__ gamma,
    const float* __restrict__ beta) {
  const long row = blockIdx.x;
  const long base = row * DDIM;
  const int t = threadIdx.x;
  const float* p = lnP + row * 8;
  const float s1 = (p[0] + p[2]) + (p[4] + p[6]);
  const float s2 = (p[1] + p[3]) + (p[5] + p[7]);
  const float mu = s1 * (1.f / DDIM);
  const float var = s2 * (1.f / DDIM) - mu * mu;
  const float rstd = rsqrtf(var + 1e-6f);
  ushort4v v = *(const ushort4v*)(y + base + t * 4);
  float4v o;
#pragma unroll
  for (int j = 0; j < 4; ++j) {
    const int c = t * 4 + j;
    o[j] = gamma[c] * ((bf2f(v[j]) - mu) * rstd) + beta[c];
  }
  *(float4v*)(out + base + t * 4) = o;
}

// ---------------- launch ----------------

extern "C" void kernel_launch(void* const* d_in, const int* in_sizes, int n_in,
                              void* d_out, int out_size, void* d_ws, size_t ws_size,
                              hipStream_t stream) {
  const float* Q = (const float*)d_in[0];
  const float* Kin = (const float*)d_in[1];
  const float* V = (const float*)d_in[2];
  const float* W1 = (const float*)d_in[3];
  const float* b1 = (const float*)d_in[4];
  const float* W2 = (const float*)d_in[5];
  const float* b2 = (const float*)d_in[6];
  const float* gamma = (const float*)d_in[7];
  const float* beta = (const float*)d_in[8];
  float* out = (float*)d_out;

  const long nQ = (long)BATCH * RDIM * DDIM;
  const long nK = (long)BATCH * UDIM * DDIM;
  const long nS = (long)BATCH * RDIM * UDIM;
  const long nRows = (long)BATCH * RDIM;  // 32768

  char* w = (char*)d_ws;
  unsigned short* Qb = (unsigned short*)w;  w += nQ * 2;
  unsigned short* Kb = (unsigned short*)w;  w += nK * 2;
  unsigned short* Vt = (unsigned short*)w;  w += nK * 2;
  unsigned short* S  = (unsigned short*)w;  w += nS * 2;
  unsigned short* X  = (unsigned short*)w;  w += nQ * 2;
  unsigned short* W1t = (unsigned short*)w; w += (long)DDIM * DDIM * 2;
  unsigned short* W2t = (unsigned short*)w; w += (long)DDIM * DDIM * 2;
  float* partP = (float*)w;                 w += nRows * 8 * 4;  // rowsums / FFN2-LN
  float* partP2 = (float*)w;                w += nRows * 8 * 4;  // X-LN partials
  unsigned short* H  = S;   // reuse: S dead after PV-gemm
  unsigned short* Y  = Kb;  // reuse: Kb dead after S-gemm

  const float scale = 1.0f / sqrtf(1024.0f + 1e-8f);

  k_conv2<<<dim3(nQ / 2048, 2), 256, 0, stream>>>(Q, Kin, Qb, Kb, scale);
  k_transpose_bf16<<<dim3(UDIM / 64, DDIM / 64, BATCH), dim3(64, 4), 0, stream>>>(
      V, Vt, UDIM, DDIM, (long)UDIM * DDIM, (long)UDIM * DDIM);
  k_transpose_bf16<<<dim3(DDIM / 64, DDIM / 64, 1), dim3(64, 4), 0, stream>>>(
      W1, W1t, DDIM, DDIM, 0, 0);
  k_transpose_bf16<<<dim3(DDIM / 64, DDIM / 64, 1), dim3(64, 4), 0, stream>>>(
      W2, W2t, DDIM, DDIM, 0, 0);

  // S = exp((Q/sqrt(D+eps)) @ K^T), row-sum partials -> partP
  gemm_bt<3><<<dim3(RDIM / 256, UDIM / 256, BATCH), 512, 0, stream>>>(
      Qb, Kb, S, UDIM, DDIM, (long)RDIM * DDIM, (long)UDIM * DDIM, (long)RDIM * UDIM,
      nullptr, nullptr, partP, nullptr, nullptr);
  // Xraw = Q + (expS @ V^T)/rowsum ; LN partials -> partP2
  gemm_bt<5><<<dim3(RDIM / 256, DDIM / 256, BATCH), 512, 0, stream>>>(
      S, Vt, X, DDIM, UDIM, (long)RDIM * UDIM, (long)DDIM * UDIM, (long)RDIM * DDIM,
      nullptr, nullptr, partP, Q, partP2);
  // X = gamma*(Xraw-mu)*rstd+beta (in-place bf16)
  k_ln_x<<<nRows, 256, 0, stream>>>(X, partP2, gamma, beta);
  // H = relu(X @ W1 + b1)
  gemm_bt<1><<<dim3(BATCH * RDIM / 256, DDIM / 256, 1), 512, 0, stream>>>(
      X, W1t, H, DDIM, DDIM, 0, 0, 0, b1, nullptr, nullptr, nullptr, nullptr);
  // Y = bf16(H @ W2 + b2 + X), LN partials -> partP
  gemm_bt<4><<<dim3(BATCH * RDIM / 256, DDIM / 256, 1), 512, 0, stream>>>(
      H, W2t, Y, DDIM, DDIM, 0, 0, 0, b2, X, partP, nullptr, nullptr);
  // out = LN(Y)
  k_ln_final<<<nRows, 256, 0, stream>>>(Y, partP, out, gamma, beta);
}

// Round 12
// 626.877 us; speedup vs baseline: 1.0401x; 1.0401x over previous
//
#include <hip/hip_runtime.h>
#include <math.h>
#include <stdint.h>

#define BATCH 16
#define RDIM 2048
#define UDIM 2048
#define DDIM 1024

typedef __attribute__((ext_vector_type(8))) short short8;
typedef __attribute__((ext_vector_type(4))) float f32x4;
typedef __attribute__((ext_vector_type(8))) unsigned short ushort8;
typedef __attribute__((ext_vector_type(4))) unsigned short ushort4v;
typedef __attribute__((ext_vector_type(4))) float float4v;

__device__ __forceinline__ float bf2f(unsigned short u) {
  unsigned int x = ((unsigned int)u) << 16;
  return __builtin_bit_cast(float, x);
}
__device__ __forceinline__ unsigned short f2bf(float f) {
  unsigned int x = __builtin_bit_cast(unsigned int, f);
  unsigned int r = (x + 0x7fffu + ((x >> 16) & 1u)) >> 16;
  return (unsigned short)r;
}

__device__ __forceinline__ void gload_lds16(const void* g, void* l) {
  __builtin_amdgcn_global_load_lds(
      (const __attribute__((address_space(1))) void*)(uintptr_t)g,
      (__attribute__((address_space(3))) void*)(uint32_t)(uintptr_t)l,
      16, 0, 0);
}

#define FENCE() __builtin_amdgcn_sched_barrier(0)
#define BAR() __builtin_amdgcn_s_barrier()
#define LGKM0() asm volatile("s_waitcnt lgkmcnt(0)" ::: "memory")
#define LGKM8() asm volatile("s_waitcnt lgkmcnt(8)" ::: "memory")
#define VMCNT6() asm volatile("s_waitcnt vmcnt(6)" ::: "memory")
#define VMCNT0() asm volatile("s_waitcnt vmcnt(0)" ::: "memory")

// ---------------- conversions ----------------

// y=0: Q -> Qb (scaled); y=1: K -> Kb
__global__ __launch_bounds__(256) void k_conv2(const float* __restrict__ Q,
                                               const float* __restrict__ Kin,
                                               unsigned short* __restrict__ Qb,
                                               unsigned short* __restrict__ Kb,
                                               float scale) {
  const float* in = blockIdx.y ? Kin : Q;
  unsigned short* out = blockIdx.y ? Kb : Qb;
  const float s = blockIdx.y ? 1.0f : scale;
  const long i = ((long)blockIdx.x * 256 + threadIdx.x) * 8;
  float4v a = *(const float4v*)(in + i);
  float4v b = *(const float4v*)(in + i + 4);
  ushort8 o;
#pragma unroll
  for (int j = 0; j < 4; ++j) o[j] = f2bf(a[j] * s);
#pragma unroll
  for (int j = 0; j < 4; ++j) o[4 + j] = f2bf(b[j] * s);
  *(ushort8*)(out + i) = o;
}

// merged transpose: z<16 -> V batch z; z==16 -> W1; z==17 -> W2
// out[c*rows + r] = bf16(in[r*cols + c])
__global__ void k_transpose_all(const float* __restrict__ V,
                                unsigned short* __restrict__ Vt,
                                const float* __restrict__ W1,
                                unsigned short* __restrict__ W1t,
                                const float* __restrict__ W2,
                                unsigned short* __restrict__ W2t) {
  __shared__ unsigned short tile[64][65];
  const int z = blockIdx.z;
  const float* in;
  unsigned short* out;
  int rows;
  if (z < 16) {
    in = V + (long)z * UDIM * DDIM;
    out = Vt + (long)z * UDIM * DDIM;
    rows = UDIM;
  } else if (z == 16) {
    in = W1; out = W1t; rows = DDIM;
  } else {
    in = W2; out = W2t; rows = DDIM;
  }
  const int cols = DDIM;
  const int r0 = blockIdx.x * 64;
  const int c0 = blockIdx.y * 64;
  if (r0 >= rows) return;  // W slices use only bx<16
  const int tx = threadIdx.x;  // 64
  const int ty = threadIdx.y;  // 4
#pragma unroll
  for (int i = 0; i < 16; ++i) {
    const int r = ty + i * 4;
    tile[r][tx] = f2bf(in[(long)(r0 + r) * cols + c0 + tx]);
  }
  __syncthreads();
#pragma unroll
  for (int i = 0; i < 16; ++i) {
    const int r = ty + i * 4;
    out[(long)(c0 + r) * rows + r0 + tx] = tile[tx][r];
  }
}

// ---------------- GEMM: C[M,N] = A[M,K] * B[N,K]^T, bf16 in, fp32 acc -------
// Core = r9/r10 (m201 8-phase, counted vmcnt(6), PMC-verified 0 bank
// conflicts). Plateau is structural: acc 128 VGPR -> 8 waves/CU max.
// EPI 0: store bf16 (PV)
// EPI 1: store bf16 relu(acc + bias[col]) (FFN1)
// EPI 3: store bf16 exp(acc) + per-block row-sum partials -> part[grow*8+by]
//        (softmax numerator; max-shift dropped: |S|<~6 so exp is safe)
// EPI 4: y = acc + bias + bf2f(res); store bf16 y + LN partials
//        -> part[grow*8 + by*2 + {0:sum,1:sumsq}]

template <int EPI>
__global__ __launch_bounds__(512, 1) void gemm_bt(
    const unsigned short* __restrict__ A, const unsigned short* __restrict__ B,
    void* __restrict__ Cout, int N, int K, long sA, long sB, long sC,
    const float* __restrict__ bias, const unsigned short* __restrict__ res,
    float* __restrict__ part) {
  __shared__ __align__(128) unsigned short lds[2][2][2][256 * 32];  // 128 KiB

  // ---- T1: XCD-aware bijective remap (all grids are multiples of 8) ----
  int lin = blockIdx.x + gridDim.x * (blockIdx.y + gridDim.y * blockIdx.z);
  lin = (lin & 7) * ((gridDim.x * gridDim.y * gridDim.z) >> 3) + (lin >> 3);
  const int by = lin % gridDim.y;  // y-fastest: share A-panel in L2
  int rest = lin / gridDim.y;
  const int bx = rest % gridDim.x;
  const int bz = rest / gridDim.x;

  const unsigned short* Ab = A + (long)bz * sA;
  const unsigned short* Bb = B + (long)bz * sB;

  const int tid = threadIdx.x;
  const int w = tid >> 6;  // 0..7
  const int lane = tid & 63;
  const int wm = w >> 2;   // 0..1
  const int wn = w & 3;    // 0..3
  const long rowBase = (long)bx * 256;
  const long colBase = (long)by * 256;

  // ---- staging addressing (involution verified 0-conflict, r4-r10) ----
  const int s = tid >> 2;                          // 0..127
  const int kslot = (tid & 3) ^ ((tid >> 3) & 3);  // logical 16B slot
  const int lRowA = s + (s & 64);                  // + h*64 at use
  const int lRowB = ((s & 96) << 1) + (s & 31);    // + h*32 at use
  const unsigned short* gA0 = Ab + (long)(rowBase + lRowA) * K + kslot * 8;
  const unsigned short* gB0 = Bb + (long)(colBase + lRowB) * K + kslot * 8;
  char* ldsB = (char*)&lds[0][0][0][0];
  const int wOff = w * 1024;

  auto STAGE_A = [&](int buf, int h, int kt) {
    const unsigned short* g = gA0 + (long)(h * 64) * K + kt * 64;
    char* d = ldsB + ((buf * 4 + 0) << 14) + h * 8192 + wOff;
    gload_lds16(g, d);
    gload_lds16(g + 32, d + 16384);
  };
  auto STAGE_B = [&](int buf, int h, int kt) {
    const unsigned short* g = gB0 + (long)(h * 32) * K + kt * 64;
    char* d = ldsB + ((buf * 4 + 2) << 14) + h * 8192 + wOff;
    gload_lds16(g, d);
    gload_lds16(g + 32, d + 16384);
  };

  const int laneM = lane & 15;
  const int laneQ = lane >> 4;
  const int swz = (laneQ ^ ((laneM >> 1) & 3)) << 4;
  const int rdA = (wm * 64 + laneM) * 64 + swz;
  const int rdB = (wn * 32 + laneM) * 64 + swz;

  f32x4 acc[8][4] = {};
  const int NT = K >> 6;
  const int NI = NT >> 1;

  short8 A0[4][2], A1[4][2], B0[2][2], B1[2][2];

  auto RD_A = [&](short8 (&dst)[4][2], int buf, int h) {
#pragma unroll
    for (int mm = 0; mm < 4; ++mm)
#pragma unroll
      for (int kk = 0; kk < 2; ++kk)
        dst[mm][kk] = *(const short8*)(ldsB + ((buf * 4 + kk) << 14) +
                                       h * 8192 + rdA + mm * 1024);
  };
  auto RD_B = [&](short8 (&dst)[2][2], int buf, int h) {
#pragma unroll
    for (int nn = 0; nn < 2; ++nn)
#pragma unroll
      for (int kk = 0; kk < 2; ++kk)
        dst[nn][kk] = *(const short8*)(ldsB + ((buf * 4 + 2 + kk) << 14) +
                                       h * 8192 + rdB + nn * 1024);
  };

#define MFMAQ(AF, BF, MB, NB)                                                  \
  __builtin_amdgcn_s_setprio(1);                                               \
  _Pragma("unroll") for (int mm = 0; mm < 4; ++mm)                             \
  _Pragma("unroll") for (int nn = 0; nn < 2; ++nn)                             \
  _Pragma("unroll") for (int kk = 0; kk < 2; ++kk)                             \
      acc[MB + mm][NB + nn] = __builtin_amdgcn_mfma_f32_16x16x32_bf16(         \
          AF[mm][kk], BF[nn][kk], acc[MB + mm][NB + nn], 0, 0, 0);             \
  __builtin_amdgcn_s_setprio(0);

  STAGE_A(0, 0, 0); STAGE_B(0, 0, 0); STAGE_B(0, 1, 0); STAGE_A(0, 1, 0);
  STAGE_A(1, 0, 1); STAGE_B(1, 0, 1); STAGE_B(1, 1, 1);
  VMCNT6();
  BAR();
  FENCE();

  for (int i = 0; i < NI; ++i) {
    const int t1 = 2 * i + 1;
    const int t2 = (2 * i + 2 <= NT - 1) ? 2 * i + 2 : NT - 1;
    const int t3 = (2 * i + 3 <= NT - 1) ? 2 * i + 3 : NT - 1;

    // ===== K-tile buf0 =====
    RD_A(A0, 0, 0); RD_B(B0, 0, 0);
    STAGE_A(1, 1, t1);
    LGKM8(); BAR(); LGKM0(); FENCE();
    MFMAQ(A0, B0, 0, 0);
    BAR();

    RD_B(B1, 0, 1);
    STAGE_A(0, 0, t2);
    BAR(); LGKM0(); FENCE();
    MFMAQ(A0, B1, 0, 2);
    BAR();

    RD_A(A1, 0, 1);
    STAGE_B(0, 0, t2);
    BAR(); LGKM0(); FENCE();
    MFMAQ(A1, B1, 4, 2);
    BAR();

    STAGE_B(0, 1, t2);
    VMCNT6(); BAR(); FENCE();
    MFMAQ(A1, B0, 4, 0);
    BAR();

    // ===== K-tile buf1 =====
    RD_A(A0, 1, 0); RD_B(B0, 1, 0);
    STAGE_A(0, 1, t2);
    LGKM8(); BAR(); LGKM0(); FENCE();
    MFMAQ(A0, B0, 0, 0);
    BAR();

    RD_B(B1, 1, 1);
    STAGE_A(1, 0, t3);
    BAR(); LGKM0(); FENCE();
    MFMAQ(A0, B1, 0, 2);
    BAR();

    RD_A(A1, 1, 1);
    STAGE_B(1, 0, t3);
    BAR(); LGKM0(); FENCE();
    MFMAQ(A1, B1, 4, 2);
    BAR();

    STAGE_B(1, 1, t3);
    VMCNT6(); BAR(); FENCE();
    MFMAQ(A1, B0, 4, 0);
    BAR();
  }
  VMCNT0();  // all trailing stage-writes to LDS landed (per-wave)
  BAR();     // ...block-wide, so LDS is safe to reuse as scratch below
#undef MFMAQ

  const long r0 = rowBase + wm * 128;
  const long c0 = colBase + wn * 64;
  const int cr = laneQ << 2;
  const int cc = laneM;

  if constexpr (EPI == 0) {
    unsigned short* C = (unsigned short*)Cout + (long)bz * sC;
#pragma unroll
    for (int i = 0; i < 8; ++i)
#pragma unroll
      for (int j = 0; j < 4; ++j)
#pragma unroll
        for (int jj = 0; jj < 4; ++jj)
          C[(r0 + i * 16 + cr + jj) * N + (c0 + j * 16 + cc)] = f2bf(acc[i][j][jj]);
  } else if constexpr (EPI == 1) {
    unsigned short* C = (unsigned short*)Cout;
#pragma unroll
    for (int i = 0; i < 8; ++i)
#pragma unroll
      for (int j = 0; j < 4; ++j)
#pragma unroll
        for (int jj = 0; jj < 4; ++jj) {
          const long col = c0 + j * 16 + cc;
          float v = acc[i][j][jj] + bias[col];
          v = fmaxf(v, 0.f);
          C[(r0 + i * 16 + cr + jj) * N + col] = f2bf(v);
        }
  } else if constexpr (EPI == 3) {
    // exp + row-sum partials (softmax numerator; PV normalizes later)
    unsigned short* C = (unsigned short*)Cout + (long)bz * sC;
    float rp[8][4];
#pragma unroll
    for (int i = 0; i < 8; ++i)
#pragma unroll
      for (int jj = 0; jj < 4; ++jj) rp[i][jj] = 0.f;
#pragma unroll
    for (int i = 0; i < 8; ++i)
#pragma unroll
      for (int j = 0; j < 4; ++j)
#pragma unroll
        for (int jj = 0; jj < 4; ++jj) {
          float e = __expf(acc[i][j][jj]);
          C[(r0 + i * 16 + cr + jj) * N + (c0 + j * 16 + cc)] = f2bf(e);
          rp[i][jj] += e;
        }
    float* sm = (float*)ldsB;
#pragma unroll
    for (int i = 0; i < 8; ++i)
#pragma unroll
      for (int jj = 0; jj < 4; ++jj) {
        float r4 = rp[i][jj];
        r4 += __shfl_xor(r4, 8);
        r4 += __shfl_xor(r4, 4);
        r4 += __shfl_xor(r4, 2);
        r4 += __shfl_xor(r4, 1);
        if (cc == 0) sm[wn * 256 + wm * 128 + i * 16 + cr + jj] = r4;
      }
    BAR();
    if (tid < 256) {
      float ssum = sm[tid] + sm[256 + tid] + sm[512 + tid] + sm[768 + tid];
      part[((long)bz * RDIM + rowBase + tid) * 8 + by] = ssum;
    }
  } else {
    // EPI 4: y bf16 + LN partials
    unsigned short* C = (unsigned short*)Cout;
    float rp1[8][4], rp2[8][4];
#pragma unroll
    for (int i = 0; i < 8; ++i)
#pragma unroll
      for (int jj = 0; jj < 4; ++jj) { rp1[i][jj] = 0.f; rp2[i][jj] = 0.f; }
#pragma unroll
    for (int i = 0; i < 8; ++i)
#pragma unroll
      for (int j = 0; j < 4; ++j)
#pragma unroll
        for (int jj = 0; jj < 4; ++jj) {
          const long row = r0 + i * 16 + cr + jj;
          const long col = c0 + j * 16 + cc;
          float v = acc[i][j][jj] + bias[col] + bf2f(res[row * N + col]);
          C[row * N + col] = f2bf(v);
          rp1[i][jj] += v;
          rp2[i][jj] += v * v;
        }
    float* sm = (float*)ldsB;
#pragma unroll
    for (int i = 0; i < 8; ++i)
#pragma unroll
      for (int jj = 0; jj < 4; ++jj) {
        float r4 = rp1[i][jj], q4 = rp2[i][jj];
        r4 += __shfl_xor(r4, 8); q4 += __shfl_xor(q4, 8);
        r4 += __shfl_xor(r4, 4); q4 += __shfl_xor(q4, 4);
        r4 += __shfl_xor(r4, 2); q4 += __shfl_xor(q4, 2);
        r4 += __shfl_xor(r4, 1); q4 += __shfl_xor(q4, 1);
        if (cc == 0) {
          sm[wn * 256 + wm * 128 + i * 16 + cr + jj] = r4;
          sm[1024 + wn * 256 + wm * 128 + i * 16 + cr + jj] = q4;
        }
      }
    BAR();
    if (tid < 256) {
      float s1 = sm[tid] + sm[256 + tid] + sm[512 + tid] + sm[768 + tid];
      float s2 = sm[1024 + tid] + sm[1280 + tid] + sm[1536 + tid] + sm[1792 + tid];
      part[(rowBase + tid) * 8 + by * 2] = s1;
      part[(rowBase + tid) * 8 + by * 2 + 1] = s2;
    }
  }
}

// ---- X = LN(Q + Va*rs) -> bf16 ; rs from S row-sum partials (8 per row) ----

__global__ __launch_bounds__(256) void k_addln_bf16(
    const float* __restrict__ Q, const unsigned short* __restrict__ Va,
    unsigned short* __restrict__ X, const float* __restrict__ gamma,
    const float* __restrict__ beta, const float* __restrict__ rsP) {
  __shared__ float red[8];
  const long row = blockIdx.x;
  const long base = row * DDIM;
  const int t = threadIdx.x;
  const float* p = rsP + row * 8;
  const float rs =
      1.0f / (((p[0] + p[1]) + (p[2] + p[3])) + ((p[4] + p[5]) + (p[6] + p[7])));
  float4v q = *(const float4v*)(Q + base + t * 4);
  ushort4v a = *(const ushort4v*)(Va + base + t * 4);
  float x[4];
  float s = 0.f, ss = 0.f;
#pragma unroll
  for (int j = 0; j < 4; ++j) {
    x[j] = q[j] + bf2f(a[j]) * rs;
    s += x[j];
    ss += x[j] * x[j];
  }
#pragma unroll
  for (int m = 32; m >= 1; m >>= 1) {
    s += __shfl_xor(s, m);
    ss += __shfl_xor(ss, m);
  }
  const int wv = t >> 6;
  if ((t & 63) == 0) {
    red[wv] = s;
    red[4 + wv] = ss;
  }
  __syncthreads();
  s = red[0] + red[1] + red[2] + red[3];
  ss = red[4] + red[5] + red[6] + red[7];
  const float mu = s * (1.f / DDIM);
  const float var = ss * (1.f / DDIM) - mu * mu;
  const float rstd = rsqrtf(var + 1e-6f);
  ushort4v o;
#pragma unroll
  for (int j = 0; j < 4; ++j) {
    const int c = t * 4 + j;
    o[j] = f2bf(gamma[c] * ((x[j] - mu) * rstd) + beta[c]);
  }
  *(ushort4v*)(X + base + t * 4) = o;
}

// ---- final LN: out = gamma*(y-mu)*rstd+beta, stats from FFN2 partials ----

__global__ __launch_bounds__(256) void k_ln_final(
    const unsigned short* __restrict__ y, const float* __restrict__ lnP,
    float* __restrict__ out, const float* __restrict__ gamma,
    const float* __restrict__ beta) {
  const long row = blockIdx.x;
  const long base = row * DDIM;
  const int t = threadIdx.x;
  const float* p = lnP + row * 8;
  const float s1 = (p[0] + p[2]) + (p[4] + p[6]);
  const float s2 = (p[1] + p[3]) + (p[5] + p[7]);
  const float mu = s1 * (1.f / DDIM);
  const float var = s2 * (1.f / DDIM) - mu * mu;
  const float rstd = rsqrtf(var + 1e-6f);
  ushort4v v = *(const ushort4v*)(y + base + t * 4);
  float4v o;
#pragma unroll
  for (int j = 0; j < 4; ++j) {
    const int c = t * 4 + j;
    o[j] = gamma[c] * ((bf2f(v[j]) - mu) * rstd) + beta[c];
  }
  *(float4v*)(out + base + t * 4) = o;
}

// ---------------- launch ----------------

extern "C" void kernel_launch(void* const* d_in, const int* in_sizes, int n_in,
                              void* d_out, int out_size, void* d_ws, size_t ws_size,
                              hipStream_t stream) {
  const float* Q = (const float*)d_in[0];
  const float* Kin = (const float*)d_in[1];
  const float* V = (const float*)d_in[2];
  const float* W1 = (const float*)d_in[3];
  const float* b1 = (const float*)d_in[4];
  const float* W2 = (const float*)d_in[5];
  const float* b2 = (const float*)d_in[6];
  const float* gamma = (const float*)d_in[7];
  const float* beta = (const float*)d_in[8];
  float* out = (float*)d_out;

  const long nQ = (long)BATCH * RDIM * DDIM;
  const long nK = (long)BATCH * UDIM * DDIM;
  const long nS = (long)BATCH * RDIM * UDIM;
  const long nRows = (long)BATCH * RDIM;  // 32768

  char* w = (char*)d_ws;
  unsigned short* Qb = (unsigned short*)w;  w += nQ * 2;
  unsigned short* Kb = (unsigned short*)w;  w += nK * 2;
  unsigned short* Vt = (unsigned short*)w;  w += nK * 2;
  unsigned short* S  = (unsigned short*)w;  w += nS * 2;
  unsigned short* X  = (unsigned short*)w;  w += nQ * 2;
  unsigned short* W1t = (unsigned short*)w; w += (long)DDIM * DDIM * 2;
  unsigned short* W2t = (unsigned short*)w; w += (long)DDIM * DDIM * 2;
  float* partP = (float*)w;                 w += nRows * 8 * 4;  // rowsums / FFN2-LN
  unsigned short* Va = Qb;  // reuse: Qb dead after S-gemm
  unsigned short* H  = S;   // reuse: S dead after PV-gemm
  unsigned short* Y  = Kb;  // reuse: Kb dead after S-gemm

  const float scale = 1.0f / sqrtf(1024.0f + 1e-8f);

  k_conv2<<<dim3(nQ / 2048, 2), 256, 0, stream>>>(Q, Kin, Qb, Kb, scale);
  k_transpose_all<<<dim3(UDIM / 64, DDIM / 64, BATCH + 2), dim3(64, 4), 0,
                    stream>>>(V, Vt, W1, W1t, W2, W2t);

  // S = exp((Q/sqrt(D+eps)) @ K^T), row-sum partials -> partP
  gemm_bt<3><<<dim3(RDIM / 256, UDIM / 256, BATCH), 512, 0, stream>>>(
      Qb, Kb, S, UDIM, DDIM, (long)RDIM * DDIM, (long)UDIM * DDIM, (long)RDIM * UDIM,
      nullptr, nullptr, partP);
  // Va_unnorm = expS @ V^T
  gemm_bt<0><<<dim3(RDIM / 256, DDIM / 256, BATCH), 512, 0, stream>>>(
      S, Vt, Va, DDIM, UDIM, (long)RDIM * UDIM, (long)DDIM * UDIM, (long)RDIM * DDIM,
      nullptr, nullptr, nullptr);
  // X = LN(Q + Va/rowsum)
  k_addln_bf16<<<nRows, 256, 0, stream>>>(Q, Va, X, gamma, beta, partP);
  // H = relu(X @ W1 + b1)
  gemm_bt<1><<<dim3(BATCH * RDIM / 256, DDIM / 256, 1), 512, 0, stream>>>(
      X, W1t, H, DDIM, DDIM, 0, 0, 0, b1, nullptr, nullptr);
  // Y = bf16(H @ W2 + b2 + X), LN partials -> partP
  gemm_bt<4><<<dim3(BATCH * RDIM / 256, DDIM / 256, 1), 512, 0, stream>>>(
      H, W2t, Y, DDIM, DDIM, 0, 0, 0, b2, X, partP);
  // out = LN(Y)
  k_ln_final<<<nRows, 256, 0, stream>>>(Y, partP, out, gamma, beta);
}